// Round 11
// baseline (129.154 us; speedup 1.0000x reference)
//
#include <hip/hip_runtime.h>

#define BATCH 16
#define IMG 96
#define NWIN 9
#define M_FILT 16
#define SP 22
#define FIN (M_FILT * SP * SP)   // 7744
#define NPP (SP * SP)            // 484

typedef float f32x2 __attribute__((ext_vector_type(2)));
typedef float f32x4 __attribute__((ext_vector_type(4)));

// Native vector ops: LLVM emits v_pk_mul_f32 / v_pk_fma_f32 for <2 x float>
// on gfx950 WITHOUT the inline-asm register-copy barriers of previous rounds.
__device__ __forceinline__ f32x2 pk_mul(f32x2 a, f32x2 b) { return a * b; }
__device__ __forceinline__ f32x2 pk_fma(f32x2 a, f32x2 b, f32x2 c) {
    return __builtin_elementwise_fma(a, b, c);
}

// Packed t(z) = 1.1 + atan(z)/pi for both halves of z.  (PROVEN Round-8 math.)
// |z|<=1: t = fma(z, P(z^2), 1.1)
// |z|>1 : t = fma(-1/z, P(1/z^2), 1.1 + copysign(0.5,z))
// P = degree-5 odd fit of atan/pi on [-1,1], exact at |u|=1 (branch continuity).
// c-constant via branch-free trunc/med3: med3(trunc(z),-1,1) = {-1,0,+1}.
__device__ __forceinline__ f32x2 dend_t2(f32x2 z, f32x2 CK0, f32x2 CK1, f32x2 CK2) {
    float rx = __builtin_amdgcn_rcpf(z.x);
    float ry = __builtin_amdgcn_rcpf(z.y);
    bool bx = __builtin_fabsf(z.x) > 1.0f;
    bool by = __builtin_fabsf(z.y) > 1.0f;
    f32x2 u;
    u.x = bx ? -rx : z.x;                      // v_cndmask w/ neg modifier
    u.y = by ? -ry : z.y;
    f32x2 s = pk_mul(u, u);
    f32x2 p = pk_fma(s, CK2, CK1);
    p = pk_fma(s, p, CK0);
    f32x2 c;
    c.x = fmaf(__builtin_amdgcn_fmed3f(truncf(z.x), -1.0f, 1.0f), 0.5f, 1.1f);
    c.y = fmaf(__builtin_amdgcn_fmed3f(truncf(z.y), -1.0f, 1.0f), 0.5f, 1.1f);
    return pk_fma(u, p, c);
}

// ---------------------------------------------------------------------------
// Kernel 1: dendrite + 4x4 maxpool. Block = one (b, m, pp-chunk):
// threads = [ di(2b) | pp_local(6b) ]; m, b block-uniform.
// {10w,-10q} pairs in 648B LDS, uniform ds_read_b64 broadcast per tap.
// Each thread: 4 dj windows as 2 packed pairs; running product over 81 taps;
// single log2 after the dj/di max reduction.
// Block 0 additionally pre-initializes out with the fc2 bias.
// ---------------------------------------------------------------------------
__global__ __launch_bounds__(256, 8) void dendrite_pool_kernel(
    const float* __restrict__ x,      // [B,96,96]
    const float* __restrict__ w,      // [16,9,9]
    const float* __restrict__ q,      // [16,9,9]
    float* __restrict__ pooled,       // [B, FIN]
    const float* __restrict__ fc2b,   // [10]
    float* __restrict__ out)          // [B, 10]
{
    const int tid   = threadIdx.x;
    const int chunk = blockIdx.x & 7;
    const int m     = (blockIdx.x >> 3) & 15;   // block-uniform
    const int b     = blockIdx.x >> 7;          // block-uniform

    if (blockIdx.x == 0 && tid < BATCH * 10) {
        out[tid] = fc2b[tid % 10];              // out = b2 (fc kernel adds on top)
    }

    __shared__ f32x2 swq[NWIN * NWIN];          // {10w, -10q} per tap
    if (tid < NWIN * NWIN) {
        float wv = w[m * 81 + tid];
        float qv = q[m * 81 + tid];
        f32x2 t; t.x = 10.0f * wv; t.y = -10.0f * qv;
        swq[tid] = t;
    }
    __syncthreads();

    const int di  = tid & 3;
    const int ppl = tid >> 2;                   // 0..63
    const int pp  = chunk * 64 + ppl;
    const int ppc = pp < NPP ? pp : (NPP - 1);  // clamp to stay in-bounds
    const int pj  = ppc % SP;
    const int pi  = ppc / SP;

    const float* xb = x + b * IMG * IMG + (pi * 4 + di) * IMG + pj * 4;

    // degree-5 odd fit of atan/pi on [-1,1]; sums to atan(1)/pi at u=1.
    const f32x2 CK0 = { 0.3167024f,  0.3167024f};
    const f32x2 CK1 = {-0.0907569f, -0.0907569f};
    const f32x2 CK2 = { 0.0240536f,  0.0240536f};

    f32x2 PA = {1.0f, 1.0f};   // windows dj=0,1
    f32x2 PB = {1.0f, 1.0f};   // windows dj=2,3

    #pragma unroll 1
    for (int r = 0; r < NWIN; ++r) {
        const f32x4* xr = reinterpret_cast<const f32x4*>(xb + r * IMG);
        f32x4 X0 = xr[0], X1 = xr[1], X2 = xr[2];
        float xs[12] = {X0.x, X0.y, X0.z, X0.w,
                        X1.x, X1.y, X1.z, X1.w,
                        X2.x, X2.y, X2.z, X2.w};

        #pragma unroll
        for (int c = 0; c < 9; ++c) {
            f32x2 wq = swq[r * 9 + c];          // uniform ds_read_b64 broadcast
            f32x2 zA, zB;
            zA.x = fmaf(xs[c + 0], wq.x, wq.y); // z = (10w)*x + (-10q)
            zA.y = fmaf(xs[c + 1], wq.x, wq.y);
            zB.x = fmaf(xs[c + 2], wq.x, wq.y);
            zB.y = fmaf(xs[c + 3], wq.x, wq.y);
            PA = pk_mul(PA, dend_t2(zA, CK0, CK1, CK2));
            PB = pk_mul(PB, dend_t2(zB, CK0, CK1, CK2));
        }
    }

    float best = fmaxf(fmaxf(PA.x, PA.y), fmaxf(PB.x, PB.y));
    best = fmaxf(best, __shfl_xor(best, 1, 64));   // di reduction
    best = fmaxf(best, __shfl_xor(best, 2, 64));
    if (di == 0 && pp < NPP) {
        pooled[b * FIN + pp * 16 + m] = __builtin_amdgcn_logf(best) * 0.69314718056f;
    }
}

// ---------------------------------------------------------------------------
// Kernel 2: fused FC1 (7744->128, bias+ReLU) + FC2 (128->10) scatter.
// One block per output neuron o (512 threads = 8 waves for latency hiding).
// After computing h[b] = relu(dot + b1[o]) for all 16 b, threads 0..159
// scatter h[b]*w2[c,o] into out[b,c] with atomics (out pre-set to b2).
// ---------------------------------------------------------------------------
__global__ __launch_bounds__(512) void fc_fused_kernel(
    const float* __restrict__ pooled,  // [B, FIN]
    const float* __restrict__ w1,      // [128, FIN]
    const float* __restrict__ b1,      // [128]
    const float* __restrict__ w2,      // [10, 128]
    float* __restrict__ out)           // [B, 10]
{
    int o = blockIdx.x;
    const float* wr = w1 + o * FIN;

    float acc[BATCH];
    #pragma unroll
    for (int b = 0; b < BATCH; ++b) acc[b] = 0.f;

    for (int f = threadIdx.x; f < FIN; f += 512) {
        float wv = wr[f];
        #pragma unroll
        for (int b = 0; b < BATCH; ++b)
            acc[b] = fmaf(pooled[b * FIN + f], wv, acc[b]);
    }

    #pragma unroll
    for (int b = 0; b < BATCH; ++b) {
        #pragma unroll
        for (int off = 32; off > 0; off >>= 1)
            acc[b] += __shfl_down(acc[b], off, 64);
    }

    __shared__ float red[8][BATCH];
    __shared__ float hrow[BATCH];
    int wid = threadIdx.x >> 6, lane = threadIdx.x & 63;
    if (lane == 0) {
        #pragma unroll
        for (int b = 0; b < BATCH; ++b) red[wid][b] = acc[b];
    }
    __syncthreads();
    if (threadIdx.x < BATCH) {
        int b = threadIdx.x;
        float s_ = b1[o];
        #pragma unroll
        for (int k = 0; k < 8; ++k) s_ += red[k][b];
        hrow[b] = fmaxf(s_, 0.f);
    }
    __syncthreads();
    if (threadIdx.x < BATCH * 10) {
        int b = threadIdx.x / 10, c = threadIdx.x % 10;
        atomicAdd(&out[b * 10 + c], hrow[b] * w2[c * 128 + o]);
    }
}

// ---------------------------------------------------------------------------
extern "C" void kernel_launch(void* const* d_in, const int* in_sizes, int n_in,
                              void* d_out, int out_size, void* d_ws, size_t ws_size,
                              hipStream_t stream)
{
    const float* x    = (const float*)d_in[0];
    const float* w    = (const float*)d_in[1];
    const float* q    = (const float*)d_in[2];
    const float* fc1w = (const float*)d_in[3];
    const float* fc1b = (const float*)d_in[4];
    const float* fc2w = (const float*)d_in[5];
    const float* fc2b = (const float*)d_in[6];
    float* out = (float*)d_out;

    float* pooled = (float*)d_ws;                 // B*FIN floats

    // grid: [ b(4b) | m(4b) | chunk(3b) ] = 2048 blocks
    dendrite_pool_kernel<<<2048, 256, 0, stream>>>(x, w, q, pooled, fc2b, out);
    fc_fused_kernel<<<128, 512, 0, stream>>>(pooled, fc1w, fc1b, fc2w, out);
}